// Round 10
// baseline (373.784 us; speedup 1.0000x reference)
//
#include <hip/hip_runtime.h>
#include <math.h>

// Problem constants
#define BB 8
#define NN 1024
#define DD 256
#define LL 512
#define KK 16          // top-(K+1)=17 picks per row
#define NROWS (BB*NN)  // 8192
#define MAXNZ 128      // per-row entry cap: 17 own + in-deg(~17, Poisson tail) + 1
#define NTERM 4        // Horner depth; dropped tail (i>=5) ~6e-5 << tolerance

// ---------------------------------------------------------------------------
// 1) Row stats + normalize: xhat = (x - mean) / (std_unbiased + 1e-6)
__global__ __launch_bounds__(64) void k_stats(const float* __restrict__ x,
                                              float* __restrict__ xhat) {
  int row = blockIdx.x;
  int l = threadIdx.x;
  const float* xr = x + (size_t)row * LL;
  float4 a = *reinterpret_cast<const float4*>(xr + l * 8);
  float4 b = *reinterpret_cast<const float4*>(xr + l * 8 + 4);
  float s = a.x + a.y + a.z + a.w + b.x + b.y + b.z + b.w;
  float sq = a.x*a.x + a.y*a.y + a.z*a.z + a.w*a.w +
             b.x*b.x + b.y*b.y + b.z*b.z + b.w*b.w;
  for (int off = 32; off >= 1; off >>= 1) {
    s  += __shfl_xor(s, off);
    sq += __shfl_xor(sq, off);
  }
  float mean = s * (1.0f / LL);
  float var = (sq - (float)LL * mean * mean) * (1.0f / (LL - 1));
  var = fmaxf(var, 0.0f);
  float inv = 1.0f / (sqrtf(var) + 1e-6f);
  float4 oa, ob;
  oa.x = (a.x - mean) * inv; oa.y = (a.y - mean) * inv;
  oa.z = (a.z - mean) * inv; oa.w = (a.w - mean) * inv;
  ob.x = (b.x - mean) * inv; ob.y = (b.y - mean) * inv;
  ob.z = (b.z - mean) * inv; ob.w = (b.w - mean) * inv;
  float* orow = xhat + (size_t)row * LL;
  *reinterpret_cast<float4*>(orow + l * 8)     = oa;
  *reinterpret_cast<float4*>(orow + l * 8 + 4) = ob;
}

// ---------------------------------------------------------------------------
// 2) corr[b] = xhat[b] @ xhat[b]^T / (L-1), UPPER-TRIANGLE tiles + mirror.
// 64x64 tile, BK=16, fp32, double-buffered LDS. fmaf k-order fixed ->
// corr bit-identical across rounds -> top-k picks stable.
__global__ __launch_bounds__(256) void k_corr(const float* __restrict__ xh,
                                              float* __restrict__ corr) {
  __shared__ float As[2][16][68];
  __shared__ float Bs[2][16][68];
  int b = blockIdx.x & 7;          // batch -> XCD round-robin
  int t = blockIdx.x >> 3;         // 0..135 upper-tri tile index
  int ti = 0, off = t;
  while (off >= 16 - ti) { off -= 16 - ti; ++ti; }
  int tj = ti + off;
  int i0 = ti * 64, j0 = tj * 64;
  int tid = threadIdx.x;
  int tr = tid >> 4, tc = tid & 15;      // 16x16 thread grid, 4x4 per thread
  int li = tid >> 2, lk = (tid & 3) * 4; // tile-load mapping
  const float* xb = xh + (size_t)b * NN * LL;
  const float* arow = xb + (size_t)(i0 + li) * LL + lk;
  const float* brow = xb + (size_t)(j0 + li) * LL + lk;

  {
    float4 va = *reinterpret_cast<const float4*>(arow);
    float4 vb = *reinterpret_cast<const float4*>(brow);
    As[0][lk + 0][li] = va.x; As[0][lk + 1][li] = va.y;
    As[0][lk + 2][li] = va.z; As[0][lk + 3][li] = va.w;
    Bs[0][lk + 0][li] = vb.x; Bs[0][lk + 1][li] = vb.y;
    Bs[0][lk + 2][li] = vb.z; Bs[0][lk + 3][li] = vb.w;
  }
  __syncthreads();

  float c[4][4] = {{0}};
  int cur = 0;
  for (int k0 = 0; k0 < LL; k0 += 16) {
    float4 na, nb;
    bool has_next = (k0 + 16 < LL);
    if (has_next) {
      na = *reinterpret_cast<const float4*>(arow + k0 + 16);
      nb = *reinterpret_cast<const float4*>(brow + k0 + 16);
    }
#pragma unroll
    for (int kk = 0; kk < 16; ++kk) {
      float4 av = *reinterpret_cast<const float4*>(&As[cur][kk][tr * 4]);
      float4 bv = *reinterpret_cast<const float4*>(&Bs[cur][kk][tc * 4]);
      c[0][0] = fmaf(av.x, bv.x, c[0][0]); c[0][1] = fmaf(av.x, bv.y, c[0][1]);
      c[0][2] = fmaf(av.x, bv.z, c[0][2]); c[0][3] = fmaf(av.x, bv.w, c[0][3]);
      c[1][0] = fmaf(av.y, bv.x, c[1][0]); c[1][1] = fmaf(av.y, bv.y, c[1][1]);
      c[1][2] = fmaf(av.y, bv.z, c[1][2]); c[1][3] = fmaf(av.y, bv.w, c[1][3]);
      c[2][0] = fmaf(av.z, bv.x, c[2][0]); c[2][1] = fmaf(av.z, bv.y, c[2][1]);
      c[2][2] = fmaf(av.z, bv.z, c[2][2]); c[2][3] = fmaf(av.z, bv.w, c[2][3]);
      c[3][0] = fmaf(av.w, bv.x, c[3][0]); c[3][1] = fmaf(av.w, bv.y, c[3][1]);
      c[3][2] = fmaf(av.w, bv.z, c[3][2]); c[3][3] = fmaf(av.w, bv.w, c[3][3]);
    }
    if (has_next) {
      int nxt = cur ^ 1;
      As[nxt][lk + 0][li] = na.x; As[nxt][lk + 1][li] = na.y;
      As[nxt][lk + 2][li] = na.z; As[nxt][lk + 3][li] = na.w;
      Bs[nxt][lk + 0][li] = nb.x; Bs[nxt][lk + 1][li] = nb.y;
      Bs[nxt][lk + 2][li] = nb.z; Bs[nxt][lk + 3][li] = nb.w;
      __syncthreads();
      cur = nxt;
    }
  }

  const float inv = 1.0f / (float)(LL - 1);
  float* cb = corr + (size_t)b * NN * NN;
#pragma unroll
  for (int r = 0; r < 4; ++r) {
    float4 o;
    o.x = c[r][0] * inv; o.y = c[r][1] * inv; o.z = c[r][2] * inv; o.w = c[r][3] * inv;
    *reinterpret_cast<float4*>(cb + (size_t)(i0 + tr * 4 + r) * NN + j0 + tc * 4) = o;
  }
  if (ti != tj) {
#pragma unroll
    for (int r = 0; r < 4; ++r) {
#pragma unroll
      for (int cc = 0; cc < 4; ++cc)
        cb[(size_t)(j0 + tc * 4 + cc) * NN + i0 + tr * 4 + r] = c[r][cc] * inv;
    }
  }
}

// ---------------------------------------------------------------------------
// 3) top-17 per row (value desc, tie -> lower index). one wave per row.
// Also zero-inits the CSR cursor for this row (k_csr runs after, in-order).
__global__ __launch_bounds__(64) void k_topk(const float* __restrict__ corr,
                                             int* __restrict__ tcols,
                                             float* __restrict__ tvals,
                                             int* __restrict__ cnt) {
  int row = blockIdx.x;
  int l = threadIdx.x;
  const float* cr = corr + (size_t)row * NN;
  float v[16];
#pragma unroll
  for (int m = 0; m < 16; ++m) v[m] = cr[m * 64 + l];
  for (int it = 0; it < KK + 1; ++it) {
    float bv = v[0]; int bm = 0;
#pragma unroll
    for (int m = 1; m < 16; ++m)
      if (v[m] > bv) { bv = v[m]; bm = m; }
    int bc = bm * 64 + l;
    for (int off = 32; off >= 1; off >>= 1) {
      float ov = __shfl_xor(bv, off);
      int oc = __shfl_xor(bc, off);
      if (ov > bv || (ov == bv && oc < bc)) { bv = ov; bc = oc; }
    }
    if ((bc & 63) == l) v[bc >> 6] = -__builtin_inff();
    if (l == 0) { tcols[row * 17 + it] = bc; tvals[row * 17 + it] = bv; }
  }
  if (l == 0) cnt[row] = 0;
}

// ---------------------------------------------------------------------------
// 4) direct CSR build: for each pick (i,j,v): append (j, 0.5v) to row i and
// (i, 0.5v) to row j; plus one identity entry (i,i,1.0) per row.
// Duplicates (i<->j mutual picks, self-pick halves) are mathematically summed
// by the gather. Entry order nondeterministic -> fp32 sum-order noise ~1e-6.
__global__ void k_csr(const int* __restrict__ tcols,
                      const float* __restrict__ tvals,
                      int* __restrict__ cnt,
                      int* __restrict__ colsA,
                      float* __restrict__ valsA) {
  int t = blockIdx.x * 256 + threadIdx.x;
  const int NT = NROWS * 17;
  if (t < NT) {
    int row = t / 17;               // global row (b*1024 + i)
    int b = row >> 10, i = row & 1023;
    int j = tcols[t];               // batch-local col
    float hv = 0.5f * tvals[t];
    int gj = b * NN + j;
    int p1 = atomicAdd(&cnt[row], 1);
    if (p1 < MAXNZ) {
      colsA[(size_t)row * MAXNZ + p1] = j;
      valsA[(size_t)row * MAXNZ + p1] = hv;
    }
    int p2 = atomicAdd(&cnt[gj], 1);
    if (p2 < MAXNZ) {
      colsA[(size_t)gj * MAXNZ + p2] = i;
      valsA[(size_t)gj * MAXNZ + p2] = hv;
    }
  } else if (t < NT + NROWS) {
    int row = t - NT;
    int p = atomicAdd(&cnt[row], 1);
    if (p < MAXNZ) {
      colsA[(size_t)row * MAXNZ + p] = row & 1023;
      valsA[(size_t)row * MAXNZ + p] = 1.0f;
    }
  }
}

// ---------------------------------------------------------------------------
// 5) deg = sum of row entries (incl. identity); Dinv = rsqrt(max(deg,1e-6))
__global__ __launch_bounds__(64) void k_deg2(const int* __restrict__ cnt,
                                             const float* __restrict__ valsA,
                                             float* __restrict__ Dinv) {
  int row = blockIdx.x;
  int l = threadIdx.x;
  int c = cnt[row]; c = c < MAXNZ ? c : MAXNZ;
  const float* vp = valsA + (size_t)row * MAXNZ;
  float s = 0.0f;
  for (int base = l; base < c; base += 64) s += vp[base];
  for (int off = 32; off >= 1; off >>= 1) s += __shfl_xor(s, off);
  if (l == 0) Dinv[row] = 1.0f / sqrtf(fmaxf(s, 1e-6f));
}

// ---------------------------------------------------------------------------
// 6) normalize entries in place: val *= Dinv_i * Dinv_j
__global__ __launch_bounds__(64) void k_norm(const int* __restrict__ cnt,
                                             const int* __restrict__ colsA,
                                             float* __restrict__ valsA,
                                             const float* __restrict__ Dinv) {
  int row = blockIdx.x;
  int l = threadIdx.x;
  int b = row >> 10;
  int c = cnt[row]; c = c < MAXNZ ? c : MAXNZ;
  float di = Dinv[row];
  for (int base = l; base < c; base += 64) {
    int j = colsA[(size_t)row * MAXNZ + base];
    valsA[(size_t)row * MAXNZ + base] *= di * Dinv[b * NN + j];
  }
}

// ---------------------------------------------------------------------------
// 7) M[k][d] = W[d][k] - alpha*(k==d); thread 0 composes d[0..NTERM]:
// coefficients of q^i in [p(dt(alpha+q))]^8, p = RK4 stability polynomial.
__global__ void k_buildM(const float* __restrict__ W,
                         const float* __restrict__ araw,
                         float* __restrict__ M,
                         float* __restrict__ dcoef) {
  float a = araw[0];
  float alpha = fminf(log1pf(expf(a)), 2.0f);
  int t = blockIdx.x * 256 + threadIdx.x;
  int k = t >> 8, d = t & 255;
  M[t] = W[d * DD + k] - (k == d ? alpha : 0.0f);
  if (t == 0) {
    const double h = 0.2 / 8.0;
    double B0 = h * (double)alpha, B1 = h;   // B(q) = h*alpha + h*q
    double T[NTERM + 1];
    for (int i = 0; i <= NTERM; ++i) T[i] = 0.0;
    T[0] = 1.0 + B0 * 0.25; T[1] = B1 * 0.25;          // 1 + B/4
    for (int kk = 3; kk >= 1; --kk) {                  // T = 1 + (B/kk)*T
      double U[NTERM + 1];
      double c0 = B0 / kk, c1 = B1 / kk;
      for (int i = 0; i <= NTERM; ++i)
        U[i] = c0 * T[i] + (i ? c1 * T[i - 1] : 0.0);
      U[0] += 1.0;
      for (int i = 0; i <= NTERM; ++i) T[i] = U[i];
    }
    double P2[NTERM + 1], P4[NTERM + 1], G[NTERM + 1];
    for (int i = 0; i <= NTERM; ++i) {
      double s = 0; for (int j = 0; j <= i; ++j) s += T[j] * T[i - j]; P2[i] = s;
    }
    for (int i = 0; i <= NTERM; ++i) {
      double s = 0; for (int j = 0; j <= i; ++j) s += P2[j] * P2[i - j]; P4[i] = s;
    }
    for (int i = 0; i <= NTERM; ++i) {
      double s = 0; for (int j = 0; j <= i; ++j) s += P4[j] * P4[i - j]; G[i] = s;
    }
    for (int i = 0; i <= NTERM; ++i) dcoef[i] = (float)G[i];
  }
}

// ---------------------------------------------------------------------------
// 8) fused Horner step: v_out = sA*((A v)@M) + sB*tokens; last: relu -> out.
// 1024 blocks (b = blk&7 XCD pinning), 8 rows/block, 256 threads.
// Gather: wave w handles rows w*2, w*2+1 via shfl-broadcast (col,val).
// y in LDS [8][256]: row-contiguous writes (conflict-free), broadcast reads.
__global__ __launch_bounds__(256) void k_q(const float* __restrict__ vin,
                                           const float* __restrict__ M,
                                           const float* __restrict__ tokens,
                                           float* __restrict__ vout,
                                           float* __restrict__ out,
                                           const int* __restrict__ cnt,
                                           const int* __restrict__ colsA,
                                           const float* __restrict__ valsA,
                                           const float* __restrict__ dcoef,
                                           int iterm, int last) {
  __shared__ __align__(16) float ylds[8][DD];   // 8 KB
  int p = blockIdx.x;
  int b = p & 7;
  int tile = p >> 3;        // 0..127
  int row0 = tile * 8;
  int tid = threadIdx.x;
  int w = tid >> 6, l = tid & 63;
  const float* xb = vin + (size_t)b * NN * DD;

  for (int rr = 0; rr < 2; ++rr) {
    int lr = w * 2 + rr;
    int grow = b * NN + row0 + lr;
    int c = cnt[grow]; c = c < MAXNZ ? c : MAXNZ;
    const int* cp = colsA + (size_t)grow * MAXNZ;
    const float* vp = valsA + (size_t)grow * MAXNZ;
    float4 acc = {0.0f, 0.0f, 0.0f, 0.0f};
    for (int base = 0; base < c; base += 64) {
      int ci = 0; float vi = 0.0f;
      if (base + l < c) { ci = cp[base + l]; vi = vp[base + l]; }
      int m = c - base; if (m > 64) m = 64;
#pragma unroll 8
      for (int s = 0; s < m; ++s) {
        int colj = __shfl(ci, s);
        float v = __shfl(vi, s);
        float4 xv = *reinterpret_cast<const float4*>(xb + (size_t)colj * DD + l * 4);
        acc.x = fmaf(v, xv.x, acc.x);
        acc.y = fmaf(v, xv.y, acc.y);
        acc.z = fmaf(v, xv.z, acc.z);
        acc.w = fmaf(v, xv.w, acc.w);
      }
    }
    *reinterpret_cast<float4*>(&ylds[lr][l * 4]) = acc;
  }
  __syncthreads();

  // term: col = tid; acc[r] = sum_k ylds[r][k] * M[k*DD + col]
  float acc[8];
#pragma unroll
  for (int r = 0; r < 8; ++r) acc[r] = 0.0f;
  const float* Mc = M + tid;
#pragma unroll 4
  for (int k0 = 0; k0 < DD; k0 += 4) {
    float m0 = Mc[(k0 + 0) * DD];
    float m1 = Mc[(k0 + 1) * DD];
    float m2 = Mc[(k0 + 2) * DD];
    float m3 = Mc[(k0 + 3) * DD];
#pragma unroll
    for (int r = 0; r < 8; ++r) {
      float4 y = *reinterpret_cast<const float4*>(&ylds[r][k0]);
      acc[r] = fmaf(y.x, m0, acc[r]);
      acc[r] = fmaf(y.y, m1, acc[r]);
      acc[r] = fmaf(y.z, m2, acc[r]);
      acc[r] = fmaf(y.w, m3, acc[r]);
    }
  }

  float sA = (iterm == 1) ? dcoef[NTERM] : 1.0f;
  float sB = dcoef[NTERM - iterm];
  size_t rowbase = (size_t)b * NN + row0;
#pragma unroll
  for (int r = 0; r < 8; ++r) {
    size_t gi = (rowbase + r) * DD + tid;
    float val = fmaf(sB, tokens[gi], sA * acc[r]);
    if (last) out[gi] = fmaxf(val, 0.0f);
    else      vout[gi] = val;
  }
}

// ---------------------------------------------------------------------------
extern "C" void kernel_launch(void* const* d_in, const int* in_sizes, int n_in,
                              void* d_out, int out_size, void* d_ws, size_t ws_size,
                              hipStream_t stream) {
  const float* tokens = (const float*)d_in[0];
  const float* x_bn   = (const float*)d_in[1];
  const float* thetaW = (const float*)d_in[2];
  const float* araw   = (const float*)d_in[3];
  float* out = (float*)d_out;

  // workspace layout (floats)
  float* ws = (float*)d_ws;
  float* xhat  = ws;                                     // 4M floats (16MB)
  float* corrA = xhat + (size_t)4 * 1024 * 1024;         // 8M floats (32MB)
  float* tvals = corrA + (size_t)8 * 1024 * 1024;
  int*   tcols = (int*)(tvals + NROWS * 17);
  float* Dinv  = (float*)(tcols + NROWS * 17);
  float* Mmat  = Dinv + NROWS;
  float* dcoef = Mmat + DD * DD;
  int*   cnt   = (int*)(dcoef + 64);
  int*   colsA = cnt + NROWS;
  float* valsA = (float*)(colsA + NROWS * MAXNZ);
  // corr region dead after k_topk: reuse for Horner ping-pong
  float* t0   = corrA;
  float* t1   = t0 + (size_t)NROWS * DD;

  k_stats<<<NROWS, 64, 0, stream>>>(x_bn, xhat);
  k_corr<<<136 * 8, 256, 0, stream>>>(xhat, corrA);
  k_topk<<<NROWS, 64, 0, stream>>>(corrA, tcols, tvals, cnt);
  k_csr<<<(NROWS * 17 + NROWS + 255) / 256, 256, 0, stream>>>(tcols, tvals, cnt,
                                                              colsA, valsA);
  k_deg2<<<NROWS, 64, 0, stream>>>(cnt, valsA, Dinv);
  k_norm<<<NROWS, 64, 0, stream>>>(cnt, colsA, valsA, Dinv);
  k_buildM<<<DD * DD / 256, 256, 0, stream>>>(thetaW, araw, Mmat, dcoef);

  // Horner: v1 = d4*(Q tokens) + d3*tokens; v_i = Q v_{i-1} + d_{N-i}*tokens
  const float* vin = tokens;
  for (int i = 1; i <= NTERM; ++i) {
    float* vo = (i & 1) ? t0 : t1;
    k_q<<<1024, 256, 0, stream>>>(vin, Mmat, tokens, vo, out, cnt, colsA, valsA,
                                  dcoef, i, i == NTERM ? 1 : 0);
    vin = vo;
  }
}